// Round 21
// baseline (31.349 us; speedup 1.0000x reference)
//
#include <hip/hip_runtime.h>
#include <hip/hip_fp16.h>

// Problem constants (fixed by setup_inputs):
//   x: (64,1,8,8) f32; KH=KW=5 -> oh=ow=4; rows n = b*16 + s, N = 1024
//   feat[n, i*5+j] = x[b*64 + (oy+i)*8 + (ox+j)], s = oy*4+ox
//   idx0:(128,36,6) in [0,25), lut0:(128,36,64)
//   idx1:(128, 6,6) in [0,36), lut1:(128, 6,64)
//   idx2:(128, 1,6) in [0, 6), lut2:(128, 1,64)
//   out[b,t,oy,ox] = b*2048 + t*16 + s
#define T_TREES 128
#define M0 36
#define M1 6
#define NNODES 43
#define TREE_SL (NNODES * 64)   // 2752
#define XPAD 67   // odd LDS image stride -> gather banks sweep residues (~2-way, free)

typedef float v2f __attribute__((ext_vector_type(2)));

__device__ __forceinline__ float sigmoidf(float v) {
    return 1.f / (1.f + __expf(-v));
}

// Pair-weight, FMA-lean: {(1-a)(1-b),(1-a)b,a(1-b),ab} per 2-row lane.
__device__ __forceinline__ void pair_w(v2f a, v2f b, v2f w[4]) {
    v2f ab = a * b;
    w[3] = ab;
    w[2] = a - ab;
    w[1] = b - ab;
    w[0] = (1.f - a) - w[1];
}

// Trilinear contraction over a row-pair; P compile-time indexed (regs).
__device__ __forceinline__ v2f lut_node_v2(const float* __restrict__ P,
                                           v2f a, v2f b, v2f c,
                                           v2f d, v2f e, v2f f) {
    v2f wa[4], wb[4], wc[4];
    pair_w(a, b, wa);
    pair_w(c, d, wb);
    pair_w(e, f, wc);
    v2f acc = {0.f, 0.f};
#pragma unroll
    for (int p = 0; p < 4; ++p) {
        v2f tp = {0.f, 0.f};
#pragma unroll
        for (int q = 0; q < 4; ++q) {
            const float* Pq = P + p * 16 + q * 4;
            v2f tq = Pq[0] * wc[0] + Pq[1] * wc[1] + Pq[2] * wc[2] + Pq[3] * wc[3];
            tp += tq * wb[q];
        }
        acc += tp * wa[p];
    }
    return acc;
}

// batch-hoist one node's 64 sigmoided LUT values from f16 LDS: 8 broadcast
// ds_read_b128 + cheap VALU converts; one batched wait then load-free FMAs.
__device__ __forceinline__ void hoist_P16(const __half2* __restrict__ src, float P[64]) {
#pragma unroll
    for (int i = 0; i < 8; ++i) {
        float4 v = reinterpret_cast<const float4*>(src)[i];   // 8 halfs
        float2 f0 = __half22float2(__builtin_bit_cast(__half2, v.x));
        float2 f1 = __half22float2(__builtin_bit_cast(__half2, v.y));
        float2 f2 = __half22float2(__builtin_bit_cast(__half2, v.z));
        float2 f3 = __half22float2(__builtin_bit_cast(__half2, v.w));
        P[8 * i + 0] = f0.x; P[8 * i + 1] = f0.y;
        P[8 * i + 2] = f1.x; P[8 * i + 3] = f1.y;
        P[8 * i + 4] = f2.x; P[8 * i + 5] = f2.y;
        P[8 * i + 6] = f3.x; P[8 * i + 7] = f3.y;
    }
}

// ===== fused kernel: block = (tree t, 256-row QUARTER), 512 thr, 4 w/SIMD =====
// The residency round. R19 (20.17us) was GRID-capped at 2 waves/SIMD (256
// blocks x 512 thr = 131072 threads); every stall model this session traces
// to that. Quarter-blocks double the thread count: 512 blocks x 512 thr ->
// 2 blocks/CU co-resident (LDS 34.4KB x 2 = 68.7KB) = 4 waves/SIMD. Price:
// hoists/CU double (86 vs 43) but f16 hoists are cheap (~+1.7us LDS), repaid
// if issue efficiency scales with residency. (512,4) caps VGPR at 128 --
// live set ~105 (P 64 + 12 gather + addr) fits; spill = R5 signature, revert.
// R20's dupx REVERTED (f16 gathers regressed: pipe is issue-bound, not
// byte-bound); f32 xs + fused ds_read2 gathers as in R19.
__global__ __launch_bounds__(512, 4) void fused_kernel(
    const float* __restrict__ x,
    const int* __restrict__ idx0, const float* __restrict__ lut0,
    const int* __restrict__ idx1, const float* __restrict__ lut1,
    const int* __restrict__ idx2, const float* __restrict__ lut2,
    float* __restrict__ out) {
    __shared__ float xs[16 * XPAD];                     //  4288 B: quarter's 16 images
    __shared__ __align__(16) __half2 Psh[NNODES * 32];  //  5504 B f16 sigmoided LUTs
    __shared__ __align__(16) __half2 h0s[M0 * 128];     // 18432 B (pair-packed f16)
    __shared__ __align__(8) float h1s[M1 * 256];        //  6144 B  => 34368 B total

    const int tid = threadIdx.x;
    const int bx = blockIdx.x;            // bx = q*128 + t (t fast -> XCD locality)
    const int t = bx & 127;
    const int q = bx >> 7;                // row quarter [0,4)

    // ---- prologue: stage 16 images + sigmoid all 43 node LUTs to f16 ----
    const float* __restrict__ xq = x + q * 1024;
    for (int i = tid; i < 1024; i += 512)
        xs[(i >> 6) * XPAD + (i & 63)] = xq[i];
    for (int i = tid; i < TREE_SL / 2; i += 512) {   // 1376 half2 elements
        int e = 2 * i;                    // even element; pair stays in one lut
        float2 v;
        if (e < M0 * 64)
            v = *reinterpret_cast<const float2*>(lut0 + t * (M0 * 64) + e);
        else if (e < (M0 + M1) * 64)
            v = *reinterpret_cast<const float2*>(lut1 + t * (M1 * 64) + (e - M0 * 64));
        else
            v = *reinterpret_cast<const float2*>(lut2 + t * 64 + (e - (M0 + M1) * 64));
        Psh[i] = __floats2half2_rn(sigmoidf(v.x), sigmoidf(v.y));
    }
    __syncthreads();

    const int w = __builtin_amdgcn_readfirstlane(tid >> 6);  // wave id 0..7
    const int ln = tid & 63;

    // ---- layer 0: wave w -> nodes w, w+8, ...; 2 pair-iters each ----
#pragma unroll 1
    for (int m = w; m < M0; m += 8) {
        float P[64];
        hoist_P16(Psh + m * 32, P);
        const int* id = idx0 + (t * M0 + m) * 6;   // wave-uniform -> scalar
        int di[6];
#pragma unroll
        for (int j = 0; j < 6; ++j) {
            int kk = id[j];
            int ii = (kk * 13) >> 6;      // kk/5 for kk in [0,25)
            di[j] = kk - 5 * ii + ii * 8; // r*8 + c window offset
        }
#pragma unroll
        for (int u = 0; u < 2; ++u) {
            int p = u * 64 + ln;          // local pair [0,128): rows 2p,2p+1
            int b = p >> 3;               // local image [0,16)
            int s = (p & 7) * 2;          // even position
            int xb = b * XPAD + (s >> 2) * 8 + (s & 3);
            v2f g[6];
#pragma unroll
            for (int j = 0; j < 6; ++j) {
                int a0 = xb + di[j];
                g[j].x = xs[a0];          // fuses -> ds_read2_b32
                g[j].y = xs[a0 + 1];
            }
            v2f r = lut_node_v2(P, g[0], g[1], g[2], g[3], g[4], g[5]);
            h0s[m * 128 + p] = __floats2half2_rn(r.x, r.y);
        }
    }
    __syncthreads();

    // ---- layer 1: waves 0-5, one node each; 2 pair-iters ----
    if (w < M1) {
        float P[64];
        hoist_P16(Psh + (M0 + w) * 32, P);
        const int* id = idx1 + (t * M1 + w) * 6;
#pragma unroll
        for (int u = 0; u < 2; ++u) {
            int p = u * 64 + ln;
            v2f g[6];
#pragma unroll
            for (int j = 0; j < 6; ++j) {
                float2 f = __half22float2(h0s[id[j] * 128 + p]);
                g[j].x = f.x; g[j].y = f.y;
            }
            v2f r = lut_node_v2(P, g[0], g[1], g[2], g[3], g[4], g[5]);
            *reinterpret_cast<v2f*>(h1s + w * 256 + 2 * p) = r;
        }
    }
    __syncthreads();

    // ---- layer 2: first 2 waves, one pair per thread (128 pairs) ----
    if (tid < 128) {
        float P[64];
        hoist_P16(Psh + (M0 + M1) * 32, P);
        const int* id = idx2 + t * 6;
        int rl = 2 * tid;                 // local even row [0,256)
        v2f g[6];
#pragma unroll
        for (int j = 0; j < 6; ++j)
            g[j] = *reinterpret_cast<const v2f*>(h1s + id[j] * 256 + rl);
        v2f o = lut_node_v2(P, g[0], g[1], g[2], g[3], g[4], g[5]);
        int row = q * 256 + rl;
        int b = row >> 4, s = row & 15;
        *reinterpret_cast<v2f*>(out + b * (T_TREES * 16) + t * 16 + s) = o;
    }
}

extern "C" void kernel_launch(void* const* d_in, const int* in_sizes, int n_in,
                              void* d_out, int out_size, void* d_ws, size_t ws_size,
                              hipStream_t stream) {
    const float* x    = (const float*)d_in[0];
    const int*   idx0 = (const int*)  d_in[1];
    const float* lut0 = (const float*)d_in[2];
    const int*   idx1 = (const int*)  d_in[3];
    const float* lut1 = (const float*)d_in[4];
    const int*   idx2 = (const int*)  d_in[5];
    const float* lut2 = (const float*)d_in[6];
    float* out = (float*)d_out;

    fused_kernel<<<dim3(4 * T_TREES), 512, 0, stream>>>(
        x, idx0, lut0, idx1, lut1, idx2, lut2, out);   // 512 blocks = 2/CU, 4 w/SIMD
}

// Round 22
// 20.051 us; speedup vs baseline: 1.5635x; 1.5635x over previous
//
#include <hip/hip_runtime.h>
#include <hip/hip_fp16.h>

// Problem constants (fixed by setup_inputs):
//   x: (64,1,8,8) f32; KH=KW=5 -> oh=ow=4; rows n = b*16 + s, N = 1024
//   feat[n, i*5+j] = x[b*64 + (oy+i)*8 + (ox+j)], s = oy*4+ox
//   idx0:(128,36,6) in [0,25), lut0:(128,36,64)
//   idx1:(128, 6,6) in [0,36), lut1:(128, 6,64)
//   idx2:(128, 1,6) in [0, 6), lut2:(128, 1,64)
//   out[b,t,oy,ox] = b*2048 + t*16 + s
//
// FINAL (R22 = R19, the session optimum, 20.17us measured):
//   single dispatch; block = (tree, 512-row half), 512 thr; 256 blocks = 1/CU.
//   Mechanisms, each proven by A/B across the session:
//   * P batch-hoisted to 64 VGPRs once per node (52->25us, R1->R4)
//   * f16 LDS for Ps and h0 (halves hoist LDS-issue; absmax 3.9e-3 << 1.19e-2)
//   * half-blocks: 43 node-hoists/CU instead of 86 (22.6->20.2us, R15->R19)
//   * row-pair v2f math (ds_read2 gathers, packed FMA)
//   * odd XPAD=67 (bank-conflict-free gathers), t-fast grid (XCD locality)
//   Refuted alternatives: occupancy-first (2 w/SIMD is structural: P needs
//   ~160 VGPR, 4 w/SIMD needs <=128 -> spills, R21); byte-halving (R20);
//   global/SGPR/coop P transport (R16/R17/R18, R10/R11/R13).
#define T_TREES 128
#define M0 36
#define M1 6
#define NNODES 43
#define TREE_SL (NNODES * 64)   // 2752
#define XPAD 67   // odd LDS image stride -> gather banks sweep residues (~2-way, free)

typedef float v2f __attribute__((ext_vector_type(2)));

__device__ __forceinline__ float sigmoidf(float v) {
    return 1.f / (1.f + __expf(-v));
}

// Pair-weight, FMA-lean: {(1-a)(1-b),(1-a)b,a(1-b),ab} per 2-row lane.
__device__ __forceinline__ void pair_w(v2f a, v2f b, v2f w[4]) {
    v2f ab = a * b;
    w[3] = ab;
    w[2] = a - ab;
    w[1] = b - ab;
    w[0] = (1.f - a) - w[1];
}

// Trilinear contraction over a row-pair; P compile-time indexed (regs).
__device__ __forceinline__ v2f lut_node_v2(const float* __restrict__ P,
                                           v2f a, v2f b, v2f c,
                                           v2f d, v2f e, v2f f) {
    v2f wa[4], wb[4], wc[4];
    pair_w(a, b, wa);
    pair_w(c, d, wb);
    pair_w(e, f, wc);
    v2f acc = {0.f, 0.f};
#pragma unroll
    for (int p = 0; p < 4; ++p) {
        v2f tp = {0.f, 0.f};
#pragma unroll
        for (int q = 0; q < 4; ++q) {
            const float* Pq = P + p * 16 + q * 4;
            v2f tq = Pq[0] * wc[0] + Pq[1] * wc[1] + Pq[2] * wc[2] + Pq[3] * wc[3];
            tp += tq * wb[q];
        }
        acc += tp * wa[p];
    }
    return acc;
}

// batch-hoist one node's 64 sigmoided LUT values from f16 LDS: 8 broadcast
// ds_read_b128 (half the LDS-pipe issue of the f32 hoist) + cheap VALU
// converts. One batched wait, then a load-free FMA stream (R4 mechanism).
__device__ __forceinline__ void hoist_P16(const __half2* __restrict__ src, float P[64]) {
#pragma unroll
    for (int i = 0; i < 8; ++i) {
        float4 v = reinterpret_cast<const float4*>(src)[i];   // 8 halfs
        float2 f0 = __half22float2(__builtin_bit_cast(__half2, v.x));
        float2 f1 = __half22float2(__builtin_bit_cast(__half2, v.y));
        float2 f2 = __half22float2(__builtin_bit_cast(__half2, v.z));
        float2 f3 = __half22float2(__builtin_bit_cast(__half2, v.w));
        P[8 * i + 0] = f0.x; P[8 * i + 1] = f0.y;
        P[8 * i + 2] = f1.x; P[8 * i + 3] = f1.y;
        P[8 * i + 4] = f2.x; P[8 * i + 5] = f2.y;
        P[8 * i + 6] = f3.x; P[8 * i + 7] = f3.y;
    }
}

// ===== single-dispatch fused kernel: block = (tree t, 512-row HALF) =====
__global__ __launch_bounds__(512) void fused_kernel(
    const float* __restrict__ x,
    const int* __restrict__ idx0, const float* __restrict__ lut0,
    const int* __restrict__ idx1, const float* __restrict__ lut1,
    const int* __restrict__ idx2, const float* __restrict__ lut2,
    float* __restrict__ out) {
    __shared__ float xs[32 * XPAD];               //  8576 B: half's 32 images
    __shared__ __align__(16) __half2 Psh[NNODES * 32];  // 5504 B sigmoided LUTs (f16)
    __shared__ __half2 h0s[M0 * 256];             // 36864 B (pair-packed f16)
    __shared__ __align__(8) float h1s[M1 * 512];  // 12288 B  => 63232 B total

    const int tid = threadIdx.x;
    const int bx = blockIdx.x;            // bx = h*128 + t (t fast -> XCD locality)
    const int t = bx & 127;
    const int h = bx >> 7;                // row half [0,2)

    // ---- prologue: stage 32 images + sigmoid all 43 node LUTs to f16 LDS ----
    const float* __restrict__ xq = x + h * 2048;
    for (int i = tid; i < 2048; i += 512)
        xs[(i >> 6) * XPAD + (i & 63)] = xq[i];
    for (int i = tid; i < TREE_SL / 2; i += 512) {   // 1376 half2 elements
        int e = 2 * i;                    // even element; pair stays in one lut
        float2 v;
        if (e < M0 * 64)
            v = *reinterpret_cast<const float2*>(lut0 + t * (M0 * 64) + e);
        else if (e < (M0 + M1) * 64)
            v = *reinterpret_cast<const float2*>(lut1 + t * (M1 * 64) + (e - M0 * 64));
        else
            v = *reinterpret_cast<const float2*>(lut2 + t * 64 + (e - (M0 + M1) * 64));
        Psh[i] = __floats2half2_rn(sigmoidf(v.x), sigmoidf(v.y));
    }
    __syncthreads();

    const int w = __builtin_amdgcn_readfirstlane(tid >> 6);  // wave id 0..7
    const int ln = tid & 63;

    // ---- layer 0: wave w -> nodes w, w+8, ...; 4 pair-iters each ----
#pragma unroll 1
    for (int m = w; m < M0; m += 8) {
        float P[64];
        hoist_P16(Psh + m * 32, P);
        const int* id = idx0 + (t * M0 + m) * 6;   // wave-uniform -> scalar
        int di[6];
#pragma unroll
        for (int j = 0; j < 6; ++j) {
            int kk = id[j];
            int ii = (kk * 13) >> 6;      // kk/5 for kk in [0,25)
            di[j] = kk - 5 * ii + ii * 8; // i*8 + j window offset
        }
#pragma unroll
        for (int u = 0; u < 4; ++u) {
            int p = u * 64 + ln;          // local pair [0,256): rows 2p,2p+1
            int b = p >> 3;               // local image [0,32)
            int s = (p & 7) * 2;          // even position
            int xb = b * XPAD + (s >> 2) * 8 + (s & 3);
            v2f g[6];
#pragma unroll
            for (int j = 0; j < 6; ++j) {
                int a0 = xb + di[j];
                g[j].x = xs[a0];          // fuses -> ds_read2_b32
                g[j].y = xs[a0 + 1];
            }
            v2f r = lut_node_v2(P, g[0], g[1], g[2], g[3], g[4], g[5]);
            h0s[m * 256 + p] = __floats2half2_rn(r.x, r.y);
        }
    }
    __syncthreads();

    // ---- layer 1: waves 0-5, one node each; 4 pair-iters ----
#pragma unroll 1
    for (int m1 = w; m1 < M1; m1 += 8) {
        float P[64];
        hoist_P16(Psh + (M0 + m1) * 32, P);
        const int* id = idx1 + (t * M1 + m1) * 6;
#pragma unroll
        for (int u = 0; u < 4; ++u) {
            int p = u * 64 + ln;
            v2f g[6];
#pragma unroll
            for (int j = 0; j < 6; ++j) {
                float2 f = __half22float2(h0s[id[j] * 256 + p]);
                g[j].x = f.x; g[j].y = f.y;
            }
            v2f r = lut_node_v2(P, g[0], g[1], g[2], g[3], g[4], g[5]);
            *reinterpret_cast<v2f*>(h1s + m1 * 512 + 2 * p) = r;
        }
    }
    __syncthreads();

    // ---- layer 2: first 4 waves, one pair per thread (256 pairs) ----
    if (tid < 256) {
        float P[64];
        hoist_P16(Psh + (M0 + M1) * 32, P);
        const int* id = idx2 + t * 6;
        int rl = 2 * tid;                 // local even row [0,512)
        v2f g[6];
#pragma unroll
        for (int j = 0; j < 6; ++j)
            g[j] = *reinterpret_cast<const v2f*>(h1s + id[j] * 512 + rl);
        v2f o = lut_node_v2(P, g[0], g[1], g[2], g[3], g[4], g[5]);
        int row = h * 512 + rl;
        int b = row >> 4, s = row & 15;
        *reinterpret_cast<v2f*>(out + b * (T_TREES * 16) + t * 16 + s) = o;
    }
}

extern "C" void kernel_launch(void* const* d_in, const int* in_sizes, int n_in,
                              void* d_out, int out_size, void* d_ws, size_t ws_size,
                              hipStream_t stream) {
    const float* x    = (const float*)d_in[0];
    const int*   idx0 = (const int*)  d_in[1];
    const float* lut0 = (const float*)d_in[2];
    const int*   idx1 = (const int*)  d_in[3];
    const float* lut1 = (const float*)d_in[4];
    const int*   idx2 = (const int*)  d_in[5];
    const float* lut2 = (const float*)d_in[6];
    float* out = (float*)d_out;

    fused_kernel<<<dim3(2 * T_TREES), 512, 0, stream>>>(
        x, idx0, lut0, idx1, lut1, idx2, lut2, out);   // 256 blocks = 1/CU
}